// Round 8
// baseline (78.582 us; speedup 1.0000x reference)
//
#include <hip/hip_runtime.h>
#include <math.h>

#define BB 16
#define NN 4096
#define DD 128
#define KK 1024
#define NPTS (BB*NN)

typedef _Float16 half8 __attribute__((ext_vector_type(8)));
typedef float f32x16 __attribute__((ext_vector_type(16)));

static __device__ __forceinline__ uint pack2(float a, float b) {
    _Float16 ha = (_Float16)a, hb = (_Float16)b;
    unsigned short ua = __builtin_bit_cast(unsigned short, ha);
    unsigned short ub = __builtin_bit_cast(unsigned short, hb);
    return (uint)ua | ((uint)ub << 16);
}

typedef __attribute__((address_space(1))) const void as1_void;
typedef __attribute__((address_space(3))) void as3_void;
static __device__ __forceinline__ void gld16(const void* g, void* l) {
    // async global->LDS, 16B/lane; LDS dest = uniform base + lane*16 (HW rule)
    __builtin_amdgcn_global_load_lds((as1_void*)g, (as3_void*)l, 16, 0, 0);
}

// counted waits + raw barrier (loads stay in flight ACROSS barriers — T3/T4)
#define VMWAIT4 asm volatile("s_waitcnt vmcnt(4)" ::: "memory")
#define VMWAIT2 asm volatile("s_waitcnt vmcnt(2)" ::: "memory")
#define VMWAIT0 asm volatile("s_waitcnt vmcnt(0)" ::: "memory")
#define LGKM0   asm volatile("s_waitcnt lgkmcnt(0)" ::: "memory")
#define RBARRIER do { __builtin_amdgcn_s_barrier(); asm volatile("" ::: "memory"); } while (0)
#define SCHEDB  __builtin_amdgcn_sched_barrier(0)

// ---------------- kernel 0a: centroid squared norms (wave per row, double shfl reduce) ----------------
__global__ void cnorm_kernel(const float* __restrict__ c, float* __restrict__ cnorm) {
    const int w = threadIdx.x >> 6, lane = threadIdx.x & 63;
    const int row = blockIdx.x * 4 + w;
    float2 v = ((const float2*)(c + (size_t)row * DD))[lane];
    double s = (double)v.x * v.x + (double)v.y * v.y;
#pragma unroll
    for (int m = 1; m < 64; m <<= 1) s += __shfl_xor(s, m);
    if (lane == 0) cnorm[row] = (float)s;
}

// ---------------- kernel 0b: pre-permute centroids into per-lane B-fragment order ----------------
// Fragment (nt, c, lane) = cent row (nt*32 + (lane&31)), d in [c*16+(lane>>5)*8, +8),
// split into fp16 hi + (lo*1024), packed as uint4 (HW-verified layout, R3-R7 pass).
__global__ void cfrag_kernel(const float* __restrict__ cent,
                             uint4* __restrict__ cfh, uint4* __restrict__ cfl) {
    const int gid = blockIdx.x * 256 + threadIdx.x;   // [0, 32*8*64)
    const int nt = gid >> 9;
    const int c = (gid >> 6) & 7;
    const int lane = gid & 63;
    const int row = nt * 32 + (lane & 31);
    const int d0 = c * 16 + (lane >> 5) * 8;
    const float* src = cent + (size_t)row * DD + d0;
    float v[8];
#pragma unroll
    for (int i = 0; i < 8; ++i) v[i] = src[i];
    float lo[8];
#pragma unroll
    for (int i = 0; i < 8; ++i) {
        _Float16 h = (_Float16)v[i];
        lo[i] = (v[i] - (float)h) * 1024.f;
    }
    uint4 h4, l4;
    h4.x = pack2(v[0], v[1]); h4.y = pack2(v[2], v[3]);
    h4.z = pack2(v[4], v[5]); h4.w = pack2(v[6], v[7]);
    l4.x = pack2(lo[0], lo[1]); l4.y = pack2(lo[2], lo[3]);
    l4.z = pack2(lo[4], lo[5]); l4.w = pack2(lo[6], lo[7]);
    cfh[gid] = h4;
    cfl[gid] = l4;
}

// ---------------- kernel 1: nearest-centroid, ring pipeline + B-reg double buffer ----------------
// 512 blocks x 4 waves; wave w owns rows [block*128+w*32, +32), A-frags in VGPRs.
// 4-slot LDS ring of half-tiles (stage s -> slot s&3). Phase h:
//   1. ds_read slot[(h+1)&3] -> NXT regs          (data for phase h+1's MFMAs)
//   2. gld16 stage h+4 -> slot[h&3]               (readers drained last phase)
//   3. 12 MFMA on CUR regs                        (NO dependency on step 1!)
//   4. epilogue (odd phases)
//   5. lgkm0 (step-1 drained; ~free) ; vmcnt(4) ; s_barrier
// vmcnt ledger: end of phase h -> stages <= h+2 landed; phase h+1 reads stage h+2. OK.
__launch_bounds__(256, 2)
__global__ void assign_mfma5(const float* __restrict__ x,
                             const uint4* __restrict__ cfh, const uint4* __restrict__ cfl,
                             const float* __restrict__ cn,
                             float* __restrict__ min_d, int* __restrict__ nearest) {
    __shared__ uint4 ring[4][8][64];   // [slot][frag-row: 0-3 hi, 4-7 lo][lane]
    __shared__ float cnS[KK];

    const int tid = threadIdx.x;
    const int lane = tid & 63;
    const int w = tid >> 6;
    const int l31 = lane & 31;
    const int lh = lane >> 5;
    const int p0 = blockIdx.x * 128 + w * 32;

    // A fragments (x rows) + per-row ||x||^2 (identical numerics to R3-R7)
    half8 ahi[8], alo[8];
    float xs = 0.f;
    const float4* xrow = (const float4*)(x + (size_t)(p0 + l31) * DD);
#pragma unroll
    for (int c = 0; c < 8; ++c) {
        float4 v0 = xrow[c * 4 + lh * 2];
        float4 v1 = xrow[c * 4 + lh * 2 + 1];
        float vv[8] = {v0.x, v0.y, v0.z, v0.w, v1.x, v1.y, v1.z, v1.w};
#pragma unroll
        for (int i = 0; i < 8; ++i) {
            _Float16 h = (_Float16)vv[i];
            ahi[c][i] = h;
            alo[c][i] = (_Float16)((vv[i] - (float)h) * 1024.f);
            xs = fmaf(vv[i], vv[i], xs);
        }
    }
    xs += __shfl_xor(xs, 32);   // lane l now has ||row l31||^2

    // cn -> LDS (consumed in epilogues; keeps the loop free of global loads)
    ((float4*)cnS)[tid] = ((const float4*)cn)[tid];

    SCHEDB;   // pin: x/cn loads retire above; gld16 issue below (exact vmcnt ledger)

    // issue stages 0..3 (2 gld16 per wave each)
#pragma unroll
    for (int s = 0; s < 4; ++s) {
        const int snt = s >> 1, sh = s & 1;
        gld16(cfh + ((size_t)(snt * 8 + sh * 4 + w)) * 64 + lane, &ring[s][w][0]);
        gld16(cfl + ((size_t)(snt * 8 + sh * 4 + w)) * 64 + lane, &ring[s][w + 4][0]);
    }

    float best[16];
    int bk[16];
#pragma unroll
    for (int r = 0; r < 16; ++r) { best[r] = INFINITY; bk[r] = 0; }

    VMWAIT4;    // stages 0,1 landed ({2,3} = 4 loads outstanding)
    LGKM0;      // own cnS ds_write done
    RBARRIER;   // all waves: stages 0,1 + cnS visible
    SCHEDB;

    // pre-read stage 0 -> B0 (CUR for phase 0)
    uint4 B0[8], B1[8];
#pragma unroll
    for (int j = 0; j < 8; ++j) B0[j] = ring[0][j][lane];

#define PHASE(NT, HALF, CURB, NXTB, DOREAD, SST, DOSTAGE, DOEPI, WAITC)              \
    {                                                                                \
        float cnv_ = 0.f;                                                            \
        if (DOEPI) cnv_ = cnS[(NT) * 32 + l31];                                      \
        if (DOREAD) {                                                                \
            const int rs_ = (2 * (NT) + (HALF) + 1) & 3;                             \
            _Pragma("unroll")                                                        \
            for (int j = 0; j < 8; ++j) NXTB[j] = ring[rs_][j][lane];                \
        }                                                                            \
        if (DOSTAGE) {                                                               \
            const int s_ = (SST);                                                    \
            const int snt_ = s_ >> 1, sh_ = s_ & 1, ss_ = s_ & 3;                    \
            gld16(cfh + ((size_t)(snt_ * 8 + sh_ * 4 + w)) * 64 + lane, &ring[ss_][w][0]);     \
            gld16(cfl + ((size_t)(snt_ * 8 + sh_ * 4 + w)) * 64 + lane, &ring[ss_][w + 4][0]); \
        }                                                                            \
        __builtin_amdgcn_s_setprio(1);                                               \
        _Pragma("unroll")                                                            \
        for (int c = 0; c < 4; ++c) {                                                \
            half8 vbh = __builtin_bit_cast(half8, CURB[c]);                          \
            half8 vbl = __builtin_bit_cast(half8, CURB[4 + c]);                      \
            hh  = __builtin_amdgcn_mfma_f32_32x32x16_f16(ahi[(HALF) * 4 + c], vbh, hh, 0, 0, 0);  \
            cr0 = __builtin_amdgcn_mfma_f32_32x32x16_f16(ahi[(HALF) * 4 + c], vbl, cr0, 0, 0, 0); \
            cr1 = __builtin_amdgcn_mfma_f32_32x32x16_f16(alo[(HALF) * 4 + c], vbh, cr1, 0, 0, 0); \
        }                                                                            \
        __builtin_amdgcn_s_setprio(0);                                               \
        if (DOEPI) {                                                                 \
            const int kcur_ = (NT) * 32 + l31;                                       \
            _Pragma("unroll")                                                        \
            for (int r = 0; r < 16; ++r) {                                           \
                float v_ = cnv_ - 2.f * hh[r] - 0.001953125f * (cr0[r] + cr1[r]);    \
                if (v_ < best[r]) { best[r] = v_; bk[r] = kcur_; }                   \
            }                                                                        \
        }                                                                            \
        WAITC;                                                                       \
    }

#define W4B do { LGKM0; VMWAIT4; RBARRIER; SCHEDB; } while (0)
#define W2B do { LGKM0; VMWAIT2; RBARRIER; SCHEDB; } while (0)
#define W0B do { LGKM0; VMWAIT0; RBARRIER; SCHEDB; } while (0)
#define WNONE do { } while (0)

#pragma unroll 1
    for (int nt = 0; nt < 30; ++nt) {
        f32x16 hh, cr0, cr1;
#pragma unroll
        for (int i = 0; i < 16; ++i) { hh[i] = 0.f; cr0[i] = 0.f; cr1[i] = 0.f; }
        PHASE(nt, 0, B0, B1, 1, 2 * nt + 4, 1, 0, W4B)
        PHASE(nt, 1, B1, B0, 1, 2 * nt + 5, 1, 1, W4B)
    }
    {   // nt = 30: staging done (last stage 63 issued at nt=29); drain 4 -> 2 -> 0
        f32x16 hh, cr0, cr1;
#pragma unroll
        for (int i = 0; i < 16; ++i) { hh[i] = 0.f; cr0[i] = 0.f; cr1[i] = 0.f; }
        PHASE(30, 0, B0, B1, 1, 0, 0, 0, W2B)
        PHASE(30, 1, B1, B0, 1, 0, 0, 1, W0B)
    }
    {   // nt = 31: everything resident; no barriers needed
        f32x16 hh, cr0, cr1;
#pragma unroll
        for (int i = 0; i < 16; ++i) { hh[i] = 0.f; cr0[i] = 0.f; cr1[i] = 0.f; }
        PHASE(31, 0, B0, B1, 1, 0, 0, 0, WNONE)
        PHASE(31, 1, B1, B0, 0, 0, 0, 1, WNONE)
    }
#undef PHASE
#undef W4B
#undef W2B
#undef W0B
#undef WNONE

    // cross-lane argmin over the 32 centroid columns (masks < 32 stay in half-wave)
#pragma unroll
    for (int r = 0; r < 16; ++r) {
        float bv = best[r]; int bi = bk[r];
#pragma unroll
        for (int m = 1; m < 32; m <<= 1) {
            float ov = __shfl_xor(bv, m);
            int oi = __shfl_xor(bi, m);
            if (ov < bv || (ov == bv && oi < bi)) { bv = ov; bi = oi; }
        }
        best[r] = bv; bk[r] = bi;
    }

    // gather ||x||^2 for this half's output rows (static shfl indices, all lanes)
    float xnv[16];
#pragma unroll
    for (int r = 0; r < 16; ++r)
        xnv[r] = __shfl(xs, (r & 3) + 8 * (r >> 2) + 4 * lh);

    if (l31 == 0) {
#pragma unroll
        for (int r = 0; r < 16; ++r) {
            int m = (r & 3) + 8 * (r >> 2) + 4 * lh;   // D-layout row (HW-verified)
            float sq = xnv[r] + best[r];
            min_d[p0 + m] = sqrtf(fmaxf(sq, 0.f));
            nearest[p0 + m] = bk[r];
        }
    }
}

// ---------------- kernel 2: per-batch stats + histogram + normalize (1024 threads) ----------------
__global__ void finalize_kernel(const float* __restrict__ min_d, const int* __restrict__ nearest,
                                const float* __restrict__ weights, float* __restrict__ out) {
    __shared__ float red[1024];
    __shared__ int hist[KK];
    __shared__ float bc[2];  // mean, thr
    const int b = blockIdx.x;
    const int tid = threadIdx.x;
    const float* md = min_d + (size_t)b * NN;
    const int* nr = nearest + (size_t)b * NN;

    // pass A: mean (two-pass std to match numpy numerics)
    float s = 0.f;
#pragma unroll
    for (int j = 0; j < NN / 1024; ++j) s += md[tid + 1024 * j];
    red[tid] = s;
    __syncthreads();
    for (int off = 512; off > 0; off >>= 1) {
        if (tid < off) red[tid] += red[tid + off];
        __syncthreads();
    }
    if (tid == 0) bc[0] = red[0] / (float)NN;
    __syncthreads();
    const float mean = bc[0];

    // pass B: sum of squared deviations -> thr = mean + std(ddof=1)
    float ss = 0.f;
#pragma unroll
    for (int j = 0; j < NN / 1024; ++j) {
        float v = md[tid + 1024 * j] - mean;
        ss += v * v;
    }
    red[tid] = ss;
    __syncthreads();
    for (int off = 512; off > 0; off >>= 1) {
        if (tid < off) red[tid] += red[tid + off];
        __syncthreads();
    }
    if (tid == 0) bc[1] = mean + sqrtf(red[0] / (float)(NN - 1));

    // histogram of masked assignments
    hist[tid] = 0;
    __syncthreads();
    const float thr = bc[1];
#pragma unroll
    for (int j = 0; j < NN / 1024; ++j) {
        int i = tid + 1024 * j;
        if (md[i] < thr) atomicAdd(&hist[nr[i]], 1);
    }
    __syncthreads();

    // asmk = counts*weights; L2-normalize the row (one k per thread)
    const float a = (float)hist[tid] * weights[tid];
    red[tid] = a * a;
    __syncthreads();
    for (int off = 512; off > 0; off >>= 1) {
        if (tid < off) red[tid] += red[tid + off];
        __syncthreads();
    }
    const float norm = sqrtf(red[0]);
    const float scale = 1.f / fmaxf(norm, 1e-12f);
    out[(size_t)b * KK + tid] = a * scale;
}

extern "C" void kernel_launch(void* const* d_in, const int* in_sizes, int n_in,
                              void* d_out, int out_size, void* d_ws, size_t ws_size,
                              hipStream_t stream) {
    const float* x = (const float*)d_in[0];
    const float* cent = (const float*)d_in[1];
    const float* weights = (const float*)d_in[2];
    float* out = (float*)d_out;

    char* ws = (char*)d_ws;
    float* min_d   = (float*)(ws + 0);
    int*   nearest = (int*)  (ws + 262144);
    float* cn      = (float*)(ws + 524288);
    uint4* cfh     = (uint4*)(ws + 528384);
    uint4* cfl     = (uint4*)(ws + 790528);

    cnorm_kernel<<<KK / 4, 256, 0, stream>>>(cent, cn);
    cfrag_kernel<<<64, 256, 0, stream>>>(cent, cfh, cfl);
    assign_mfma5<<<NPTS / 128, 256, 0, stream>>>(x, cfh, cfl, cn, min_d, nearest);
    finalize_kernel<<<BB, 1024, 0, stream>>>(min_d, nearest, weights, out);
}